// Round 1
// baseline (2063.857 us; speedup 1.0000x reference)
//
#include <hip/hip_runtime.h>
#include <hip/hip_bf16.h>
#include <math.h>

// Loss_26886495273741: uniformity loss
//   dots = F F^T (diag masked), I = argmax_row(dots), d = ||F - F[I] + eps||_2
//   loss = -mean(log(n*d))
// F: [16384, 256] fp32.
//
// Kernel 1: fused tiled matmul + per-row running argmax (fp32 vector ALU).
//   Each block: 32-row stripe, A panel persistent in LDS (K-major, swizzled),
//   loops over all 128-column tiles with BK=32 chunks, register prefetch.
// Kernel 2: per-row distance + log term, per-block double partial sums.
// Kernel 3: final reduce -> scalar loss.

#define NROWS 16384
#define DIM   256
#define BM    32
#define BN    128
#define BK    32
#define NTILE (NROWS / BN)            // 128
#define NCHUNK (NTILE * (DIM / BK))   // 1024
#define EPSF  1e-6f

__global__ __launch_bounds__(256, 2)
void nn_argmax_kernel(const float* __restrict__ F, int* __restrict__ I)
{
    __shared__ float As[DIM * BM];   // 32 KB, [k][m'] swizzled, persistent panel
    __shared__ float Bs[BK * BN];    // 16 KB, [k'][c'] swizzled, per-chunk

    const int tid  = threadIdx.x;
    const int tx   = tid & 31;        // column group 0..31 (4 cols each)
    const int ty   = tid >> 5;        // row group 0..7 (4 rows each)
    const int row0 = blockIdx.x * BM;

    // ---------- stage A: rows [row0, row0+32) x all K, K-major swizzled ----------
    #pragma unroll
    for (int q = 0; q < 8; ++q) {
        const int f  = tid + (q << 8);      // 0..2047 float4 slots
        const int m  = f >> 6;              // 0..31 row in stripe
        const int kq = f & 63;              // k-quad
        const int k  = kq << 2;
        const float4 v = *reinterpret_cast<const float4*>(
            F + (size_t)(row0 + m) * DIM + k);
        const int s   = kq & 7;
        const int pos = ((((m >> 2) ^ s) << 2) | (m & 3));
        As[(k + 0) * BM + pos] = v.x;
        As[(k + 1) * BM + pos] = v.y;
        As[(k + 2) * BM + pos] = v.z;
        As[(k + 3) * BM + pos] = v.w;
    }

    // ---------- fixed per-thread B staging geometry ----------
    int bc[4], bk[4], bpos[4];
    #pragma unroll
    for (int q = 0; q < 4; ++q) {
        const int f  = tid + (q << 8);      // 0..1023 float4 slots per chunk
        bc[q] = f >> 3;                     // col 0..127
        const int kq = f & 7;
        bk[q] = kq << 2;                    // k' in {0,4,...,28}
        bpos[q] = ((((bc[q] >> 2) ^ kq) << 2) | (bc[q] & 3));
    }

    float acc[4][4];
    #pragma unroll
    for (int i = 0; i < 4; ++i)
        #pragma unroll
        for (int j = 0; j < 4; ++j) acc[i][j] = 0.f;

    float bestv[4];
    int   besti[4];
    #pragma unroll
    for (int i = 0; i < 4; ++i) { bestv[i] = -3.4e38f; besti[i] = 0; }

    // prefetch chunk 0 (tile 0, kc 0)
    float4 cur[4], nxt[4];
    #pragma unroll
    for (int q = 0; q < 4; ++q) {
        cur[q] = *reinterpret_cast<const float4*>(F + (size_t)bc[q] * DIM + bk[q]);
        nxt[q] = cur[q];
    }

    for (int cc = 0; cc < NCHUNK; ++cc) {
        const int kc   = cc & 7;
        const int col0 = (cc >> 3) * BN;

        __syncthreads();   // previous compute finished reading Bs
        #pragma unroll
        for (int q = 0; q < 4; ++q) {
            Bs[(bk[q] + 0) * BN + bpos[q]] = cur[q].x;
            Bs[(bk[q] + 1) * BN + bpos[q]] = cur[q].y;
            Bs[(bk[q] + 2) * BN + bpos[q]] = cur[q].z;
            Bs[(bk[q] + 3) * BN + bpos[q]] = cur[q].w;
        }
        if (cc + 1 < NCHUNK) {   // prefetch next chunk into registers
            const int nc    = cc + 1;
            const int ncol0 = (nc >> 3) * BN;
            const int nk0   = (nc & 7) * BK;
            #pragma unroll
            for (int q = 0; q < 4; ++q)
                nxt[q] = *reinterpret_cast<const float4*>(
                    F + (size_t)(ncol0 + bc[q]) * DIM + nk0 + bk[q]);
        }
        __syncthreads();   // Bs ready

        const int kbase = kc * BK;
        #pragma unroll
        for (int kq = 0; kq < 8; ++kq) {
            #pragma unroll
            for (int i4 = 0; i4 < 4; ++i4) {
                const int kp = (kq << 2) + i4;
                const float4 a = *reinterpret_cast<const float4*>(
                    As + (kbase + kp) * BM + ((ty ^ kq) << 2));
                const float4 b = *reinterpret_cast<const float4*>(
                    Bs + kp * BN + ((tx ^ kq) << 2));
                acc[0][0] += a.x * b.x; acc[0][1] += a.x * b.y;
                acc[0][2] += a.x * b.z; acc[0][3] += a.x * b.w;
                acc[1][0] += a.y * b.x; acc[1][1] += a.y * b.y;
                acc[1][2] += a.y * b.z; acc[1][3] += a.y * b.w;
                acc[2][0] += a.z * b.x; acc[2][1] += a.z * b.y;
                acc[2][2] += a.z * b.z; acc[2][3] += a.z * b.w;
                acc[3][0] += a.w * b.x; acc[3][1] += a.w * b.y;
                acc[3][2] += a.w * b.z; acc[3][3] += a.w * b.w;
            }
        }

        if (kc == 7) {   // tile done: fold 4x4 dots into per-row running argmax
            #pragma unroll
            for (int i = 0; i < 4; ++i) {
                const int r = row0 + (ty << 2) + i;
                #pragma unroll
                for (int j = 0; j < 4; ++j) {
                    const int c = col0 + (tx << 2) + j;
                    const float v = acc[i][j];
                    if (c != r && (v > bestv[i] || (v == bestv[i] && c < besti[i]))) {
                        bestv[i] = v; besti[i] = c;
                    }
                    acc[i][j] = 0.f;
                }
            }
        }
        #pragma unroll
        for (int q = 0; q < 4; ++q) cur[q] = nxt[q];
    }

    // cross-lane argmax reduce over the 32 tx lanes (stays within 32-lane halves)
    #pragma unroll
    for (int i = 0; i < 4; ++i) {
        float bv = bestv[i]; int bi = besti[i];
        #pragma unroll
        for (int m = 16; m >= 1; m >>= 1) {
            const float ov = __shfl_xor(bv, m);
            const int   oi = __shfl_xor(bi, m);
            if (ov > bv || (ov == bv && oi < bi)) { bv = ov; bi = oi; }
        }
        if (tx == 0) I[row0 + (ty << 2) + i] = bi;
    }
}

__global__ __launch_bounds__(256)
void dist_loss_kernel(const float* __restrict__ F, const int* __restrict__ I,
                      double* __restrict__ partials)
{
    const int tid  = threadIdx.x;
    const int lane = tid & 63;
    const int w    = tid >> 6;                 // wave in block: 0..3
    const int gw   = blockIdx.x * 4 + w;       // global wave: 0..1023
    double local = 0.0;
    for (int r = gw; r < NROWS; r += 1024) {   // 16 rows per wave
        const int idx = I[r];
        const float4 a = *reinterpret_cast<const float4*>(
            F + (size_t)r * DIM + (lane << 2));
        const float4 b = *reinterpret_cast<const float4*>(
            F + (size_t)idx * DIM + (lane << 2));
        const float dx = a.x - b.x + EPSF;
        const float dy = a.y - b.y + EPSF;
        const float dz = a.z - b.z + EPSF;
        const float dw = a.w - b.w + EPSF;
        float ss = dx * dx + dy * dy + dz * dz + dw * dw;
        #pragma unroll
        for (int m = 32; m >= 1; m >>= 1) ss += __shfl_xor(ss, m);
        if (lane == 0)
            local += 0.5 * log((double)ss) + log((double)NROWS);
    }
    __shared__ double sm[4];
    if (lane == 0) sm[w] = local;
    __syncthreads();
    if (tid == 0) partials[blockIdx.x] = sm[0] + sm[1] + sm[2] + sm[3];
}

__global__ __launch_bounds__(256)
void finalize_kernel(const double* __restrict__ partials, float* __restrict__ out)
{
    const int tid = threadIdx.x;
    double v = partials[tid];
    #pragma unroll
    for (int m = 32; m >= 1; m >>= 1) v += __shfl_xor(v, m);
    __shared__ double sm[4];
    if ((tid & 63) == 0) sm[tid >> 6] = v;
    __syncthreads();
    if (tid == 0) out[0] = (float)(-(sm[0] + sm[1] + sm[2] + sm[3]) / (double)NROWS);
}

extern "C" void kernel_launch(void* const* d_in, const int* in_sizes, int n_in,
                              void* d_out, int out_size, void* d_ws, size_t ws_size,
                              hipStream_t stream)
{
    const float* F   = (const float*)d_in[0];
    float*       out = (float*)d_out;
    int*    Iidx     = (int*)d_ws;
    double* partials = (double*)((char*)d_ws + (size_t)NROWS * sizeof(int));

    nn_argmax_kernel<<<NROWS / BM, 256, 0, stream>>>(F, Iidx);
    dist_loss_kernel<<<256, 256, 0, stream>>>(F, Iidx, partials);
    finalize_kernel<<<1, 256, 0, stream>>>(partials, out);
}

// Round 2
// 386.676 us; speedup vs baseline: 5.3374x; 5.3374x over previous
//
#include <hip/hip_runtime.h>
#include <hip/hip_bf16.h>
#include <math.h>

// Loss_26886495273741: uniformity loss
//   dots = F F^T (diag masked), I = argmax_row(dots), d = ||F - F[I] + eps||_2
//   loss = -mean(log(n*d))
// F: [16384, 256] fp32.
//
// Round 2: bf16 MFMA similarity + fused per-row argmax.
//   K0 convert: fp32 -> bf16 (round-to-nearest-even), zero packed-argmax array
//   K1 mfma_argmax: 128x128 tile, BK=32, mfma_f32_16x16x32_bf16,
//      global_load_lds(16B) staging, epilogue shuffle-argmax + u64 atomicMax
//      (packed monotonic-float | inverted-index => smallest-index tie-break)
//   K2 dist_loss: exact fp32 distances with picked indices (unchanged math)
//   K3 finalize

#define NROWS 16384
#define DIM   256
#define BM    128
#define BN    128
#define BK    32
#define EPSF  1e-6f

typedef __attribute__((ext_vector_type(8))) __bf16 bf16x8;
typedef __attribute__((ext_vector_type(4))) float f32x4;

typedef const __attribute__((address_space(1))) void* gas1_t;
typedef __attribute__((address_space(3))) void* las3_t;

__device__ __forceinline__ void glds16(const void* g, void* l) {
    __builtin_amdgcn_global_load_lds((gas1_t)g, (las3_t)l, 16, 0, 0);
}

__device__ __forceinline__ unsigned short f2bf(float f) {
    union { float f; unsigned u; } x; x.f = f;
    const unsigned u = x.u;
    return (unsigned short)((u + 0x7FFFu + ((u >> 16) & 1u)) >> 16);  // RNE
}

// ---------------- K0: convert fp32 -> bf16, zero packed ----------------
__global__ __launch_bounds__(256)
void convert_kernel(const float* __restrict__ F, unsigned short* __restrict__ Fb,
                    unsigned long long* __restrict__ packed)
{
    const int t = blockIdx.x * 256 + threadIdx.x;     // 2048*256 = 524288 threads
    const float4 a = *reinterpret_cast<const float4*>(F + (size_t)t * 8);
    const float4 b = *reinterpret_cast<const float4*>(F + (size_t)t * 8 + 4);
    ushort4 lo, hi;
    lo.x = f2bf(a.x); lo.y = f2bf(a.y); lo.z = f2bf(a.z); lo.w = f2bf(a.w);
    hi.x = f2bf(b.x); hi.y = f2bf(b.y); hi.z = f2bf(b.z); hi.w = f2bf(b.w);
    *reinterpret_cast<ushort4*>(Fb + (size_t)t * 8)     = lo;
    *reinterpret_cast<ushort4*>(Fb + (size_t)t * 8 + 4) = hi;
    if (t < NROWS) packed[t] = 0ull;                  // below any finite mapped value
}

// ---------------- K1: bf16 MFMA similarity + per-row argmax ----------------
__global__ __launch_bounds__(256, 3)
void mfma_argmax_kernel(const unsigned short* __restrict__ Fb,
                        unsigned long long* __restrict__ packed)
{
    __shared__ __align__(16) unsigned short As[BM * BK];   // 8 KB, [row][k] linear
    __shared__ __align__(16) unsigned short Bs[BN * BK];   // 8 KB, [col][k] linear

    const int tid  = threadIdx.x;
    const int w    = tid >> 6;          // wave 0..3
    const int l    = tid & 63;
    const int row0 = (int)(blockIdx.x >> 7) * BM;
    const int col0 = (int)(blockIdx.x & 127) * BN;
    const int wrow = (w >> 1) * 64;     // wave's 64x64 sub-tile
    const int wcol = (w & 1) * 64;

    f32x4 acc[4][4] = {};

    // staging geometry: issue q covers rows q*64 + w*16 + (l>>2), chunk (l&3)*8
    const int srow = l >> 2;
    const int skc  = (l & 3) * 8;

    for (int kt = 0; kt < DIM / BK; ++kt) {
        const int k0 = kt * BK;
        __syncthreads();   // prior MFMA reads of LDS done (vmcnt/lgkm drained)
        #pragma unroll
        for (int q = 0; q < 2; ++q) {
            glds16(Fb + (size_t)(row0 + q * 64 + w * 16 + srow) * DIM + k0 + skc,
                   &As[q * 2048 + w * 512]);
            glds16(Fb + (size_t)(col0 + q * 64 + w * 16 + srow) * DIM + k0 + skc,
                   &Bs[q * 2048 + w * 512]);
        }
        __syncthreads();   // staging landed (compiler drains vmcnt before barrier)

        bf16x8 af[4], bfr[4];
        #pragma unroll
        for (int i = 0; i < 4; ++i)
            af[i] = *reinterpret_cast<const bf16x8*>(
                &As[(wrow + i * 16 + (l & 15)) * BK + (l >> 4) * 8]);
        #pragma unroll
        for (int j = 0; j < 4; ++j)
            bfr[j] = *reinterpret_cast<const bf16x8*>(
                &Bs[(wcol + j * 16 + (l & 15)) * BK + (l >> 4) * 8]);
        #pragma unroll
        for (int i = 0; i < 4; ++i)
            #pragma unroll
            for (int j = 0; j < 4; ++j)
                acc[i][j] = __builtin_amdgcn_mfma_f32_16x16x32_bf16(
                    af[i], bfr[j], acc[i][j], 0, 0, 0);
    }

    // epilogue: per-row argmax over this block's 128 columns
    // C/D layout: col = lane&15, row = (lane>>4)*4 + reg
    const int lc  = l & 15;
    const int lr4 = l >> 4;
    #pragma unroll
    for (int i = 0; i < 4; ++i) {
        #pragma unroll
        for (int reg = 0; reg < 4; ++reg) {
            const int r = row0 + wrow + i * 16 + lr4 * 4 + reg;
            float bv = -3.4e38f; int bc = 0x7FFFFFFF;
            #pragma unroll
            for (int j = 0; j < 4; ++j) {
                const int c = col0 + wcol + j * 16 + lc;
                const float v = acc[i][j][reg];
                if (c != r && (v > bv || (v == bv && c < bc))) { bv = v; bc = c; }
            }
            #pragma unroll
            for (int m = 8; m >= 1; m >>= 1) {     // reduce over the 16-lane col group
                const float ov = __shfl_xor(bv, m);
                const int   oi = __shfl_xor(bc, m);
                if (ov > bv || (ov == bv && oi < bc)) { bv = ov; bc = oi; }
            }
            if (lc == 0) {
                unsigned u = __float_as_uint(bv);
                unsigned mu = (u & 0x80000000u) ? ~u : (u | 0x80000000u);
                const unsigned long long pk =
                    ((unsigned long long)mu << 32) | (0xFFFFFFFFu - (unsigned)bc);
                atomicMax(&packed[r], pk);
            }
        }
    }
}

// ---------------- K2: exact fp32 distances + log terms ----------------
__global__ __launch_bounds__(256)
void dist_loss_kernel(const float* __restrict__ F,
                      const unsigned long long* __restrict__ packed,
                      double* __restrict__ partials)
{
    const int tid  = threadIdx.x;
    const int lane = tid & 63;
    const int w    = tid >> 6;
    const int gw   = blockIdx.x * 4 + w;       // 1024 waves
    double local = 0.0;
    for (int r = gw; r < NROWS; r += 1024) {
        const unsigned long long p = packed[r];
        const int idx = (int)(0xFFFFFFFFu - (unsigned)(p & 0xFFFFFFFFull));
        const float4 a = *reinterpret_cast<const float4*>(
            F + (size_t)r * DIM + (lane << 2));
        const float4 b = *reinterpret_cast<const float4*>(
            F + (size_t)idx * DIM + (lane << 2));
        const float dx = a.x - b.x + EPSF;
        const float dy = a.y - b.y + EPSF;
        const float dz = a.z - b.z + EPSF;
        const float dw = a.w - b.w + EPSF;
        float ss = dx * dx + dy * dy + dz * dz + dw * dw;
        #pragma unroll
        for (int m = 32; m >= 1; m >>= 1) ss += __shfl_xor(ss, m);
        if (lane == 0)
            local += 0.5 * log((double)ss) + log((double)NROWS);
    }
    __shared__ double sm[4];
    if (lane == 0) sm[w] = local;
    __syncthreads();
    if (tid == 0) partials[blockIdx.x] = sm[0] + sm[1] + sm[2] + sm[3];
}

__global__ __launch_bounds__(256)
void finalize_kernel(const double* __restrict__ partials, float* __restrict__ out)
{
    const int tid = threadIdx.x;
    double v = partials[tid];
    #pragma unroll
    for (int m = 32; m >= 1; m >>= 1) v += __shfl_xor(v, m);
    __shared__ double sm[4];
    if ((tid & 63) == 0) sm[tid >> 6] = v;
    __syncthreads();
    if (tid == 0) out[0] = (float)(-(sm[0] + sm[1] + sm[2] + sm[3]) / (double)NROWS);
}

extern "C" void kernel_launch(void* const* d_in, const int* in_sizes, int n_in,
                              void* d_out, int out_size, void* d_ws, size_t ws_size,
                              hipStream_t stream)
{
    const float* F   = (const float*)d_in[0];
    float*       out = (float*)d_out;

    unsigned short*     Fb       = (unsigned short*)d_ws;                       // 8 MB
    unsigned long long* packed   = (unsigned long long*)((char*)d_ws + (size_t)NROWS * DIM * 2);
    double*             partials = (double*)((char*)packed + (size_t)NROWS * 8);

    convert_kernel<<<2048, 256, 0, stream>>>(F, Fb, packed);
    mfma_argmax_kernel<<<(NROWS / BM) * (NROWS / BN), 256, 0, stream>>>(Fb, packed);
    dist_loss_kernel<<<256, 256, 0, stream>>>(F, packed, partials);
    finalize_kernel<<<1, 256, 0, stream>>>(partials, out);
}

// Round 3
// 173.909 us; speedup vs baseline: 11.8675x; 2.2234x over previous
//
#include <hip/hip_runtime.h>
#include <hip/hip_bf16.h>
#include <math.h>

// Loss_26886495273741: uniformity loss
//   dots = F F^T (diag masked), I = argmax_row(dots), d = ||F - F[I] + eps||_2
//   loss = -mean(log(n*d))
// F: [16384, 256] fp32.
//
// Round 3: row-stripe persistent MFMA kernel.
//   Grid = 128 row-stripes x 8 col-chunks (chunk = blockIdx&7 -> XCD affinity).
//   A panel [128][256] bf16 resident in LDS (64 KB, XOR-swizzled via
//   pre-permuted global_load_lds source); B slice [128 cols][32 K] double-
//   buffered (16 KB), one barrier per K-step, prefetch in flight.
//   Per-tile in-register argmax fold; cross-lane reduce + packed u64
//   atomicMax once per block (65k atomics total vs 2M before).

#define NROWS 16384
#define DIM   256
#define BM    128
#define BN    128
#define BK    32
#define CCOLS 2048               // cols per chunk
#define TILES (CCOLS / BN)       // 16
#define EPSF  1e-6f

typedef __attribute__((ext_vector_type(8))) __bf16 bf16x8;
typedef __attribute__((ext_vector_type(4))) float f32x4;

typedef const __attribute__((address_space(1))) void* gas1_t;
typedef __attribute__((address_space(3))) void* las3_t;

__device__ __forceinline__ void glds16(const void* g, void* l) {
    __builtin_amdgcn_global_load_lds((gas1_t)g, (las3_t)l, 16, 0, 0);
}

__device__ __forceinline__ unsigned short f2bf(float f) {
    union { float f; unsigned u; } x; x.f = f;
    const unsigned u = x.u;
    return (unsigned short)((u + 0x7FFFu + ((u >> 16) & 1u)) >> 16);  // RNE
}

// ---------------- K0: convert fp32 -> bf16, zero packed ----------------
__global__ __launch_bounds__(256)
void convert_kernel(const float* __restrict__ F, unsigned short* __restrict__ Fb,
                    unsigned long long* __restrict__ packed)
{
    const int t = blockIdx.x * 256 + threadIdx.x;     // 524288 threads
    const float4 a = *reinterpret_cast<const float4*>(F + (size_t)t * 8);
    const float4 b = *reinterpret_cast<const float4*>(F + (size_t)t * 8 + 4);
    ushort4 lo, hi;
    lo.x = f2bf(a.x); lo.y = f2bf(a.y); lo.z = f2bf(a.z); lo.w = f2bf(a.w);
    hi.x = f2bf(b.x); hi.y = f2bf(b.y); hi.z = f2bf(b.z); hi.w = f2bf(b.w);
    *reinterpret_cast<ushort4*>(Fb + (size_t)t * 8)     = lo;
    *reinterpret_cast<ushort4*>(Fb + (size_t)t * 8 + 4) = hi;
    if (t < NROWS) packed[t] = 0ull;
}

// ---------------- K1: row-stripe bf16 MFMA + per-row argmax ----------------
__global__ __launch_bounds__(256, 2)
void mfma_rowstripe_kernel(const unsigned short* __restrict__ Fb,
                           unsigned long long* __restrict__ packed)
{
    __shared__ __align__(16) unsigned short As[BM * DIM];      // 64 KB swizzled
    __shared__ __align__(16) unsigned short Bs[2 * BN * BK];   // 16 KB dbuf

    const int tid   = threadIdx.x;
    const int w     = tid >> 6;
    const int l     = tid & 63;
    const int chunk = (int)blockIdx.x & 7;         // -> XCD affinity
    const int rs    = (int)blockIdx.x >> 3;
    const int row0  = rs * BM;
    const int ccol0 = chunk * CCOLS;

    const int wrow = (w >> 1) * 64;
    const int wcol = (w & 1) * 64;
    const int lc   = l & 15;
    const int lr4  = l >> 4;

    // ---- stage A panel once: LDS phys (row, p) holds global chunk p^(row&7) ----
    {
        const int lr = l >> 5;                        // 0..1
        const int sc = (l & 31) ^ (2 * w + lr);       // pre-permuted source chunk
        #pragma unroll
        for (int t = 0; t < 16; ++t) {
            const int r = 8 * t + 2 * w + lr;
            glds16(Fb + (size_t)(row0 + r) * DIM + sc * 8,
                   &As[(t * 4 + w) * 512]);
        }
    }

    // ---- B staging geometry: phys (col, p) holds window chunk p^((col>>1)&3) ----
    const int bcl = l >> 2;                           // col within 16-col group
    const int bsc = (l & 3) ^ ((l >> 3) & 3);         // pre-permuted source chunk

    // stage B for (tile=0, kt=0) into buf 0
    #pragma unroll
    for (int t = 0; t < 2; ++t) {
        const int c = ccol0 + (t * 4 + w) * 16 + bcl;
        glds16(Fb + (size_t)c * DIM + bsc * 8, &Bs[(t * 4 + w) * 512]);
    }

    f32x4 acc[4][4] = {};
    float bestv[4][4];
    int   bestc[4][4];
    #pragma unroll
    for (int i = 0; i < 4; ++i)
        #pragma unroll
        for (int g = 0; g < 4; ++g) { bestv[i][g] = -3.4e38f; bestc[i][g] = 0; }

    int cur = 0;
    for (int tile = 0; tile < TILES; ++tile) {
        const int tcol0 = ccol0 + tile * BN;
        for (int kt = 0; kt < 8; ++kt) {
            __syncthreads();   // buf[cur] + (first iter) A panel staged; prior reads done
            const int step = tile * 8 + kt;
            if (step + 1 < TILES * 8) {               // prefetch next B slice
                const int ns = step + 1;
                const int nc0 = ccol0 + (ns >> 3) * BN;
                const int nk0 = (ns & 7) * BK;
                #pragma unroll
                for (int t = 0; t < 2; ++t) {
                    const int c = nc0 + (t * 4 + w) * 16 + bcl;
                    glds16(Fb + (size_t)c * DIM + nk0 + bsc * 8,
                           &Bs[(cur ^ 1) * 2048 + (t * 4 + w) * 512]);
                }
            }
            bf16x8 af[4], bfv[4];
            #pragma unroll
            for (int i = 0; i < 4; ++i) {
                const int r = wrow + i * 16 + lc;
                const int g = kt * 4 + lr4;
                af[i] = *reinterpret_cast<const bf16x8*>(
                    &As[r * 256 + ((g ^ (r & 7)) << 3)]);
            }
            #pragma unroll
            for (int j = 0; j < 4; ++j) {
                const int c = wcol + j * 16 + lc;
                const int p = lr4 ^ ((c >> 1) & 3);
                bfv[j] = *reinterpret_cast<const bf16x8*>(
                    &Bs[cur * 2048 + c * 32 + p * 8]);
            }
            #pragma unroll
            for (int i = 0; i < 4; ++i)
                #pragma unroll
                for (int j = 0; j < 4; ++j)
                    acc[i][j] = __builtin_amdgcn_mfma_f32_16x16x32_bf16(
                        af[i], bfv[j], acc[i][j], 0, 0, 0);
            cur ^= 1;
        }

        // ---- fold this tile into the running per-row argmax ----
        if (row0 == tcol0) {   // the one diagonal tile: mask c==r
            #pragma unroll
            for (int i = 0; i < 4; ++i)
                #pragma unroll
                for (int g = 0; g < 4; ++g) {
                    const int r = wrow + i * 16 + lr4 * 4 + g;
                    #pragma unroll
                    for (int j = 0; j < 4; ++j) {
                        const int c = wcol + j * 16 + lc;
                        if (c == r) acc[i][j][g] = -3.4e38f;
                    }
                }
        }
        #pragma unroll
        for (int i = 0; i < 4; ++i)
            #pragma unroll
            for (int g = 0; g < 4; ++g)
                #pragma unroll
                for (int j = 0; j < 4; ++j) {
                    const float v = acc[i][j][g];
                    const int   c = tcol0 + wcol + j * 16 + lc;
                    if (v > bestv[i][g]) { bestv[i][g] = v; bestc[i][g] = c; }
                    acc[i][j][g] = 0.f;
                }
    }

    // ---- once per block: reduce over the 16-lane col group, one atomic ----
    #pragma unroll
    for (int i = 0; i < 4; ++i)
        #pragma unroll
        for (int g = 0; g < 4; ++g) {
            float bv = bestv[i][g]; int bc = bestc[i][g];
            #pragma unroll
            for (int m = 8; m >= 1; m >>= 1) {
                const float ov = __shfl_xor(bv, m);
                const int   oi = __shfl_xor(bc, m);
                if (ov > bv || (ov == bv && oi < bc)) { bv = ov; bc = oi; }
            }
            if (lc == 0) {
                const int r = row0 + wrow + i * 16 + lr4 * 4 + g;
                const unsigned u  = __float_as_uint(bv);
                const unsigned mu = (u & 0x80000000u) ? ~u : (u | 0x80000000u);
                atomicMax(&packed[r], ((unsigned long long)mu << 32) |
                                      (0xFFFFFFFFu - (unsigned)bc));
            }
        }
}

// ---------------- K2: exact fp32 distances + log terms ----------------
__global__ __launch_bounds__(256)
void dist_loss_kernel(const float* __restrict__ F,
                      const unsigned long long* __restrict__ packed,
                      double* __restrict__ partials)
{
    const int tid  = threadIdx.x;
    const int lane = tid & 63;
    const int w    = tid >> 6;
    const int gw   = blockIdx.x * 4 + w;       // 1024 waves
    double local = 0.0;
    for (int r = gw; r < NROWS; r += 1024) {
        const unsigned long long p = packed[r];
        const int idx = (int)(0xFFFFFFFFu - (unsigned)(p & 0xFFFFFFFFull));
        const float4 a = *reinterpret_cast<const float4*>(
            F + (size_t)r * DIM + (lane << 2));
        const float4 b = *reinterpret_cast<const float4*>(
            F + (size_t)idx * DIM + (lane << 2));
        const float dx = a.x - b.x + EPSF;
        const float dy = a.y - b.y + EPSF;
        const float dz = a.z - b.z + EPSF;
        const float dw = a.w - b.w + EPSF;
        float ss = dx * dx + dy * dy + dz * dz + dw * dw;
        #pragma unroll
        for (int m = 32; m >= 1; m >>= 1) ss += __shfl_xor(ss, m);
        if (lane == 0)
            local += 0.5 * log((double)ss) + log((double)NROWS);
    }
    __shared__ double sm[4];
    if (lane == 0) sm[w] = local;
    __syncthreads();
    if (tid == 0) partials[blockIdx.x] = sm[0] + sm[1] + sm[2] + sm[3];
}

__global__ __launch_bounds__(256)
void finalize_kernel(const double* __restrict__ partials, float* __restrict__ out)
{
    const int tid = threadIdx.x;
    double v = partials[tid];
    #pragma unroll
    for (int m = 32; m >= 1; m >>= 1) v += __shfl_xor(v, m);
    __shared__ double sm[4];
    if ((tid & 63) == 0) sm[tid >> 6] = v;
    __syncthreads();
    if (tid == 0) out[0] = (float)(-(sm[0] + sm[1] + sm[2] + sm[3]) / (double)NROWS);
}

extern "C" void kernel_launch(void* const* d_in, const int* in_sizes, int n_in,
                              void* d_out, int out_size, void* d_ws, size_t ws_size,
                              hipStream_t stream)
{
    const float* F   = (const float*)d_in[0];
    float*       out = (float*)d_out;

    unsigned short*     Fb       = (unsigned short*)d_ws;                       // 8 MB
    unsigned long long* packed   = (unsigned long long*)((char*)d_ws + (size_t)NROWS * DIM * 2);
    double*             partials = (double*)((char*)packed + (size_t)NROWS * 8);

    convert_kernel<<<2048, 256, 0, stream>>>(F, Fb, packed);
    mfma_rowstripe_kernel<<<(NROWS / BM) * 8, 256, 0, stream>>>(Fb, packed);
    dist_loss_kernel<<<256, 256, 0, stream>>>(F, packed, partials);
    finalize_kernel<<<1, 256, 0, stream>>>(partials, out);
}